// Round 1
// baseline (1242.765 us; speedup 1.0000x reference)
//
#include <hip/hip_runtime.h>

#define TS 16            // output tile side (per block)
#define UROWS 62         // 2*TS + 30 halo rows of upsampled data
#define USTRIDE 68       // LDS row stride in floats (272 B = 17*16B, +4-bank shift/row)
#define INH 128
#define LEAK 0.01f

__global__ __launch_bounds__(256)
void afa_fused(const float* __restrict__ x, const float* __restrict__ filt,
               float* __restrict__ out) {
    __shared__ float tile[UROWS * USTRIDE];
    const int tid = threadIdx.x;
    const int tx = tid & 15, ty = tid >> 4;
    const int Jb = blockIdx.x * TS;
    const int Ib = blockIdx.y * TS;
    const int bc = blockIdx.z;                 // 0..511 = B*C
    const float* __restrict__ xc = x + (size_t)bc * (INH * INH);

    const float UPS = (float)(127.0 / 255.0); // upsample scale, f32-rounded like ref
    const float DNS = (float)(255.0 / 127.0); // downsample scale

    const int ur0 = 2 * Ib - 15;               // tile origin in upsampled coords
    const int uc0 = 2 * Jb - 15;

    // ---- stage: bilinear upsample + leaky_relu into LDS (zeros outside = conv padding) ----
    for (int idx = tid; idx < UROWS * UROWS; idx += 256) {
        unsigned lr = (unsigned)idx / UROWS;
        unsigned lc = (unsigned)idx - lr * UROWS;
        int r = ur0 + (int)lr, s = uc0 + (int)lc;
        float val = 0.0f;
        if ((unsigned)r < 256u && (unsigned)s < 256u) {
            float cr = (float)r * UPS;
            int r0 = (int)cr; if (r0 > 126) r0 = 126;
            float wr = cr - (float)r0;
            float cs = (float)s * UPS;
            int s0 = (int)cs; if (s0 > 126) s0 = 126;
            float ws = cs - (float)s0;
            const float* p = xc + r0 * INH + s0;
            float a = p[0], b = p[1], c = p[INH], d = p[INH + 1];
            float top = a + (c - a) * wr;      // interp rows first (matches reference order)
            float bot = b + (d - b) * wr;
            val = top + (bot - top) * ws;
            val = (val > 0.0f) ? val : (LEAK * val);
        }
        tile[lr * USTRIDE + lc] = val;
    }
    __syncthreads();

    // ---- conv 31x31 at the 4 positions (2i..2i+1, 2j..2j+1), fused downsample ----
    float acc00 = 0.f, acc01 = 0.f, acc10 = 0.f, acc11 = 0.f;
    const float* rowbase = &tile[(2 * ty) * USTRIDE + 2 * tx];

    #pragma unroll 1
    for (int k = 0; k < 32; ++k) {
        const float* row = rowbase + k * USTRIDE;
        float buf[32];
        #pragma unroll
        for (int q = 0; q < 16; ++q) {
            float2 v = *(const float2*)(row + 2 * q);   // 8B-aligned, bank-conflict-free
            buf[2 * q] = v.x; buf[2 * q + 1] = v.y;
        }
        if (k < 31) {                                   // filter row k -> F[2i, *]
            const float* fr = filt + k * 31;
            #pragma unroll
            for (int v = 0; v < 31; ++v) {
                float f = fr[v];
                acc00 = fmaf(buf[v], f, acc00);
                acc01 = fmaf(buf[v + 1], f, acc01);
            }
        }
        if (k > 0) {                                    // filter row k-1 -> F[2i+1, *]
            const float* fr = filt + (k - 1) * 31;
            #pragma unroll
            for (int v = 0; v < 31; ++v) {
                float f = fr[v];
                acc10 = fmaf(buf[v], f, acc10);
                acc11 = fmaf(buf[v + 1], f, acc11);
            }
        }
    }

    // ---- bilinear downsample combine (rows first, then cols — reference order) ----
    const int i = Ib + ty, j = Jb + tx;
    float ciy = (float)i * DNS;
    float wy = ciy - (float)(2 * i);
    float cjx = (float)j * DNS;
    float wx = cjx - (float)(2 * j);
    float v0 = acc00 + (acc10 - acc00) * wy;
    float v1 = acc01 + (acc11 - acc01) * wy;
    float o  = v0 + (v1 - v0) * wx;
    out[((size_t)bc * 128 + i) * 128 + j] = o;
}

extern "C" void kernel_launch(void* const* d_in, const int* in_sizes, int n_in,
                              void* d_out, int out_size, void* d_ws, size_t ws_size,
                              hipStream_t stream) {
    const float* x    = (const float*)d_in[0];   // (8,64,128,128) f32
    const float* filt = (const float*)d_in[1];   // (31,31) f32
    float* out = (float*)d_out;                  // (8,64,128,128) f32
    dim3 grid(128 / TS, 128 / TS, 8 * 64);
    afa_fused<<<grid, dim3(256), 0, stream>>>(x, filt, out);
}

// Round 2
// 867.241 us; speedup vs baseline: 1.4330x; 1.4330x over previous
//
#include <hip/hip_runtime.h>

#define INH 128
#define LEAK 0.01f
#define OT 32            // output tile side per block (32x32 outputs)
#define TROWS 94         // 2*OT + 30 halo rows of upsampled data
#define TSTR 96          // LDS row stride in floats (16B-aligned rows)

__global__ __launch_bounds__(256)
void afa_fused(const float* __restrict__ x, const float* __restrict__ filt,
               float* __restrict__ out) {
    __shared__ float tile[TROWS * TSTR];
    const int tid = threadIdx.x;
    const int tx = tid & 15, ty = tid >> 4;     // 16x16 threads, each does 2x2 outputs
    const int Jb = blockIdx.x * OT;             // output col origin
    const int Ib = blockIdx.y * OT;             // output row origin
    const int bc = blockIdx.z;                  // 0..511 = B*C
    const float* __restrict__ xc = x + (size_t)bc * (INH * INH);

    const float UPS = (float)(127.0 / 255.0);
    const float DNS = (float)(255.0 / 127.0);

    const int ur0 = 2 * Ib - 15;                // tile origin in upsampled coords
    const int uc0 = 2 * Jb - 15;

    // ---- stage: bilinear upsample + leaky_relu into LDS (zeros outside = conv padding) ----
    for (int idx = tid; idx < TROWS * TROWS; idx += 256) {
        unsigned lr = (unsigned)idx / TROWS;
        unsigned lc = (unsigned)idx - lr * TROWS;
        int r = ur0 + (int)lr, s = uc0 + (int)lc;
        float val = 0.0f;
        if ((unsigned)r < 256u && (unsigned)s < 256u) {
            float cr = (float)r * UPS;
            int r0 = (int)cr; if (r0 > 126) r0 = 126;
            float wr = cr - (float)r0;
            float cs = (float)s * UPS;
            int s0 = (int)cs; if (s0 > 126) s0 = 126;
            float ws = cs - (float)s0;
            const float* p = xc + r0 * INH + s0;
            float a = p[0], b = p[1], c = p[INH], d = p[INH + 1];
            float top = a + (c - a) * wr;
            float bot = b + (d - b) * wr;
            val = top + (bot - top) * ws;
            val = (val > 0.0f) ? val : (LEAK * val);
        }
        tile[lr * TSTR + lc] = val;
    }
    __syncthreads();

    // ---- conv 31x31 at 4x4 conv points per thread (2x2 output pixels), fused downsample ----
    // Thread covers conv rows 4ty..4ty+3 and conv cols 4tx..4tx+3 (block-relative).
    // tile row (4ty + r) holds filter row fk = r - cr for conv row cr.
    float acc[4][4];
    #pragma unroll
    for (int a = 0; a < 4; ++a)
        #pragma unroll
        for (int b = 0; b < 4; ++b) acc[a][b] = 0.0f;

    const float* rowbase = &tile[(4 * ty) * TSTR + 4 * tx];

    #pragma unroll 1
    for (int r = 0; r < 34; ++r) {
        const float* row = rowbase + r * TSTR;
        float d[36];
        #pragma unroll
        for (int q = 0; q < 9; ++q)
            *(float4*)&d[4 * q] = *(const float4*)(row + 4 * q);

        #pragma unroll
        for (int cr = 0; cr < 4; ++cr) {
            int fk = r - cr;
            if (fk < 0 || fk > 30) continue;        // wave-uniform branch
            const float* fr = filt + fk * 31;
            #pragma unroll
            for (int fc = 0; fc < 31; ++fc) {
                float f = fr[fc];
                #pragma unroll
                for (int cc = 0; cc < 4; ++cc)
                    acc[cr][cc] = fmaf(d[fc + cc], f, acc[cr][cc]);
            }
        }
    }

    // ---- bilinear downsample combine (rows first, then cols — reference order) ----
    #pragma unroll
    for (int a = 0; a < 2; ++a) {
        int io = Ib + 2 * ty + a;
        float ciy = (float)io * DNS;
        float wy = ciy - (float)(2 * io);
        #pragma unroll
        for (int b = 0; b < 2; ++b) {
            int jo = Jb + 2 * tx + b;
            float cjx = (float)jo * DNS;
            float wx = cjx - (float)(2 * jo);
            float v0 = acc[2 * a][2 * b]     + (acc[2 * a + 1][2 * b]     - acc[2 * a][2 * b])     * wy;
            float v1 = acc[2 * a][2 * b + 1] + (acc[2 * a + 1][2 * b + 1] - acc[2 * a][2 * b + 1]) * wy;
            float o  = v0 + (v1 - v0) * wx;
            out[((size_t)bc * 128 + io) * 128 + jo] = o;
        }
    }
}

extern "C" void kernel_launch(void* const* d_in, const int* in_sizes, int n_in,
                              void* d_out, int out_size, void* d_ws, size_t ws_size,
                              hipStream_t stream) {
    const float* x    = (const float*)d_in[0];   // (8,64,128,128) f32
    const float* filt = (const float*)d_in[1];   // (31,31) f32
    float* out = (float*)d_out;                  // (8,64,128,128) f32
    dim3 grid(128 / OT, 128 / OT, 8 * 64);
    afa_fused<<<grid, dim3(256), 0, stream>>>(x, filt, out);
}

// Round 3
// 862.538 us; speedup vs baseline: 1.4408x; 1.0055x over previous
//
#include <hip/hip_runtime.h>

#define INH 128
#define LEAK 0.01f
#define OT 32            // output tile side per block (32x32 outputs)
#define TROWS 94         // 2*OT + 30 halo rows of upsampled data
#define TSTR 96          // LDS row stride in floats (384B rows)

// XOR swizzle: permute 16B chunks within each 64B window by row. Spreads the
// 4 ty-groups of a wave (row stride 384B = bank 0 mod 32) across bank-quads.
__device__ __forceinline__ int swz_of_row(int row) { return ((row >> 2) & 3) << 2; }

__device__ __forceinline__ void load_row(float* __restrict__ d,
                                         const float* __restrict__ tile,
                                         int row, int col4) {
    const int base = row * TSTR + col4;
    const int s = swz_of_row(row);
    #pragma unroll
    for (int q = 0; q < 9; ++q)
        *(float4*)&d[4 * q] = *(const float4*)&tile[(base + 4 * q) ^ s];
}

__device__ __forceinline__ void fma_rows(const float* __restrict__ d, int r,
                                         const float* __restrict__ filt,
                                         float acc[4][4]) {
    #pragma unroll
    for (int cr = 0; cr < 4; ++cr) {
        int fk = r - cr;
        if (fk < 0 || fk > 30) continue;          // wave-uniform branch
        const float* fr = filt + fk * 31;
        #pragma unroll
        for (int fc = 0; fc < 31; ++fc) {
            float f = fr[fc];
            #pragma unroll
            for (int cc = 0; cc < 4; ++cc)
                acc[cr][cc] = fmaf(d[fc + cc], f, acc[cr][cc]);
        }
    }
}

__global__ __launch_bounds__(256)
void afa_fused(const float* __restrict__ x, const float* __restrict__ filt,
               float* __restrict__ out) {
    __shared__ float tile[TROWS * TSTR];
    const int tid = threadIdx.x;
    const int tx = tid & 15, ty = tid >> 4;     // 16x16 threads, each 2x2 outputs
    const int Jb = blockIdx.x * OT;
    const int Ib = blockIdx.y * OT;
    const int bc = blockIdx.z;                  // 0..511 = B*C
    const float* __restrict__ xc = x + (size_t)bc * (INH * INH);

    const float UPS = (float)(127.0 / 255.0);
    const float DNS = (float)(255.0 / 127.0);

    const int ur0 = 2 * Ib - 15;
    const int uc0 = 2 * Jb - 15;

    // ---- stage: bilinear upsample + leaky_relu into LDS (zeros outside = conv padding) ----
    for (int idx = tid; idx < TROWS * TROWS; idx += 256) {
        unsigned lr = (unsigned)idx / TROWS;
        unsigned lc = (unsigned)idx - lr * TROWS;
        int r = ur0 + (int)lr, s = uc0 + (int)lc;
        float val = 0.0f;
        if ((unsigned)r < 256u && (unsigned)s < 256u) {
            float cr = (float)r * UPS;
            int r0 = (int)cr; if (r0 > 126) r0 = 126;
            float wr = cr - (float)r0;
            float cs = (float)s * UPS;
            int s0 = (int)cs; if (s0 > 126) s0 = 126;
            float ws = cs - (float)s0;
            const float* p = xc + r0 * INH + s0;
            float a = p[0], b = p[1], c = p[INH], d = p[INH + 1];
            float top = a + (c - a) * wr;
            float bot = b + (d - b) * wr;
            val = top + (bot - top) * ws;
            val = (val > 0.0f) ? val : (LEAK * val);
        }
        tile[((int)lr * TSTR + (int)lc) ^ swz_of_row((int)lr)] = val;
    }
    __syncthreads();

    // ---- conv 31x31 at 4x4 conv points per thread, register-double-buffered rows ----
    float acc[4][4];
    #pragma unroll
    for (int a = 0; a < 4; ++a)
        #pragma unroll
        for (int b = 0; b < 4; ++b) acc[a][b] = 0.0f;

    const int row0 = 4 * ty;      // first tile row this thread touches
    const int col4 = 4 * tx;      // 16B-aligned column start

    float dA[36], dB[36];
    load_row(dA, tile, row0 + 0, col4);

    #pragma unroll 1
    for (int r = 0; r < 34; r += 2) {
        load_row(dB, tile, row0 + r + 1, col4);     // prefetch next row
        fma_rows(dA, r, filt, acc);
        if (r + 2 < 34) load_row(dA, tile, row0 + r + 2, col4);
        fma_rows(dB, r + 1, filt, acc);
    }

    // ---- bilinear downsample combine (rows first, then cols — reference order) ----
    #pragma unroll
    for (int a = 0; a < 2; ++a) {
        int io = Ib + 2 * ty + a;
        float ciy = (float)io * DNS;
        float wy = ciy - (float)(2 * io);
        #pragma unroll
        for (int b = 0; b < 2; ++b) {
            int jo = Jb + 2 * tx + b;
            float cjx = (float)jo * DNS;
            float wx = cjx - (float)(2 * jo);
            float v0 = acc[2 * a][2 * b]     + (acc[2 * a + 1][2 * b]     - acc[2 * a][2 * b])     * wy;
            float v1 = acc[2 * a][2 * b + 1] + (acc[2 * a + 1][2 * b + 1] - acc[2 * a][2 * b + 1]) * wy;
            float o  = v0 + (v1 - v0) * wx;
            out[((size_t)bc * 128 + io) * 128 + jo] = o;
        }
    }
}

extern "C" void kernel_launch(void* const* d_in, const int* in_sizes, int n_in,
                              void* d_out, int out_size, void* d_ws, size_t ws_size,
                              hipStream_t stream) {
    const float* x    = (const float*)d_in[0];   // (8,64,128,128) f32
    const float* filt = (const float*)d_in[1];   // (31,31) f32
    float* out = (float*)d_out;                  // (8,64,128,128) f32
    dim3 grid(128 / OT, 128 / OT, 8 * 64);
    afa_fused<<<grid, dim3(256), 0, stream>>>(x, filt, out);
}

// Round 4
// 201.597 us; speedup vs baseline: 6.1646x; 4.2785x over previous
//
#include <hip/hip_runtime.h>
#include <hip/hip_bf16.h>

typedef __attribute__((ext_vector_type(8))) short bf16x8;
typedef __attribute__((ext_vector_type(16))) float f32x16;

#define INH   128
#define LEAK  0.01f
#define USTR  120          // LDS row stride in bf16 (240B; 60 dwords ≡ 4 mod 8 → ≤2-way banks)
#define UROWS 158          // 128 conv rows + 30 halo

__device__ __forceinline__ unsigned short f2bf(float f) {
    __hip_bfloat16 h = __float2bfloat16(f);
    return *(unsigned short*)&h;
}

// ---------- kernel 1: Toeplitz filter fragment table (d_ws, 31*4*64*16 B = 124 KB) ----------
// Fragment (fr,c): B[k][j] = f[fr][16c + k - j], k=8*(lane>>5)+t, j=lane&31; zero outside [0,30].
__global__ void build_table(const float* __restrict__ filt, unsigned short* __restrict__ tab) {
    int idx = blockIdx.x * 256 + threadIdx.x;          // (fr*4+c)*64 + lane
    if (idx >= 31 * 4 * 64) return;
    int lane = idx & 63, c = (idx >> 6) & 3, fr = idx >> 8;
    #pragma unroll
    for (int t = 0; t < 8; ++t) {
        int v = 16 * c + 8 * (lane >> 5) + t - (lane & 31);
        float f = (v >= 0 && v <= 30) ? filt[fr * 31 + v] : 0.0f;
        tab[idx * 8 + t] = f2bf(f);
    }
}

// ---------- kernel 2: fused upsample+act (LDS bf16) -> MFMA conv -> downsample ----------
__global__ __launch_bounds__(256)
void afa_mfma(const float* __restrict__ x, const unsigned short* __restrict__ tab,
              float* __restrict__ out) {
    __shared__ unsigned short U[UROWS * USTR];         // 37920 B
    const int tid = threadIdx.x;
    const int bx = blockIdx.x;                         // 0..3  (64 conv cols)
    const int by = blockIdx.y;                         // 0..1  (128 conv rows)
    const int bc = blockIdx.z;                         // 0..511
    const float* __restrict__ xc = x + (size_t)bc * (INH * INH);

    const float UPS = (float)(127.0 / 255.0);
    const float DNS = (float)(255.0 / 127.0);
    const int pr0 = 128 * by, pc0 = 64 * bx;           // padded-coord origins

    // ---- stage: bilinear upsample + leaky_relu -> bf16 LDS (zeros = conv padding & col pad) ----
    for (int idx = tid; idx < UROWS * (USTR / 2); idx += 256) {
        int lr = idx / (USTR / 2);
        int lc0 = (idx - lr * (USTR / 2)) * 2;
        unsigned pack = 0;
        #pragma unroll
        for (int e = 0; e < 2; ++e) {
            int lc = lc0 + e;
            int ur = pr0 + lr - 15;                    // conv zero-pad shift
            int uc = pc0 + lc - 15;
            float val = 0.0f;
            if (lc < 96 && (unsigned)ur < 256u && (unsigned)uc < 256u) {
                float cr = (float)ur * UPS;
                int r0 = (int)cr; if (r0 > 126) r0 = 126;
                float wr = cr - (float)r0;
                float cs = (float)uc * UPS;
                int s0 = (int)cs; if (s0 > 126) s0 = 126;
                float ws = cs - (float)s0;
                const float* p = xc + r0 * INH + s0;
                float a = p[0], b = p[1], c = p[INH], d = p[INH + 1];
                float top = a + (c - a) * wr;
                float bot = b + (d - b) * wr;
                val = top + (bot - top) * ws;
                val = (val > 0.0f) ? val : (LEAK * val);
            }
            pack |= (unsigned)f2bf(val) << (16 * e);
        }
        *(unsigned*)&U[lr * USTR + lc0] = pack;
    }
    __syncthreads();

    // ---- conv: per wave, one 32-col strip x two 32-row tiles; fr-outer, Toeplitz B from table ----
    const int lane = tid & 63;
    const int w = tid >> 6;                            // wave 0..3
    const int wxs = w & 1, wys = w >> 1;               // col-strip / row-half
    const int r32 = lane & 31;                         // A row i  (and C col j in epilogue)
    const int hk = lane >> 5;                          // k-chunk half

    const char* ub = (const char*)U + (64 * wys + r32) * (USTR * 2) + (32 * wxs + 8 * hk) * 2;
    const bf16x8* tv = (const bf16x8*)tab;

    f32x16 acc0 = {0.f,0.f,0.f,0.f,0.f,0.f,0.f,0.f,0.f,0.f,0.f,0.f,0.f,0.f,0.f,0.f};
    f32x16 acc1 = acc0;

    #pragma unroll 1
    for (int fr = 0; fr < 31; ++fr) {
        bf16x8 B0 = tv[(fr * 4 + 0) * 64 + lane];
        bf16x8 B1 = tv[(fr * 4 + 1) * 64 + lane];
        bf16x8 B2 = tv[(fr * 4 + 2) * 64 + lane];
        bf16x8 B3 = tv[(fr * 4 + 3) * 64 + lane];
        const char* u0 = ub + fr * (USTR * 2);
        const char* u1 = u0 + 32 * (USTR * 2);
        bf16x8 a;
        a = *(const bf16x8*)(u0 + 0);
        acc0 = __builtin_amdgcn_mfma_f32_32x32x16_bf16(a, B0, acc0, 0, 0, 0);
        a = *(const bf16x8*)(u0 + 32);
        acc0 = __builtin_amdgcn_mfma_f32_32x32x16_bf16(a, B1, acc0, 0, 0, 0);
        a = *(const bf16x8*)(u0 + 64);
        acc0 = __builtin_amdgcn_mfma_f32_32x32x16_bf16(a, B2, acc0, 0, 0, 0);
        a = *(const bf16x8*)(u0 + 96);
        acc0 = __builtin_amdgcn_mfma_f32_32x32x16_bf16(a, B3, acc0, 0, 0, 0);
        a = *(const bf16x8*)(u1 + 0);
        acc1 = __builtin_amdgcn_mfma_f32_32x32x16_bf16(a, B0, acc1, 0, 0, 0);
        a = *(const bf16x8*)(u1 + 32);
        acc1 = __builtin_amdgcn_mfma_f32_32x32x16_bf16(a, B1, acc1, 0, 0, 0);
        a = *(const bf16x8*)(u1 + 64);
        acc1 = __builtin_amdgcn_mfma_f32_32x32x16_bf16(a, B2, acc1, 0, 0, 0);
        a = *(const bf16x8*)(u1 + 96);
        acc1 = __builtin_amdgcn_mfma_f32_32x32x16_bf16(a, B3, acc1, 0, 0, 0);
    }

    // ---- epilogue: bilinear downsample (rows in-lane via reg pairs, cols via shfl_xor) ----
    const int cc = 64 * bx + 32 * wxs + r32;           // conv col of this lane (C col j)
    const bool doout = (cc & 1) == 0;
    const int oj = cc >> 1;
    const float wxw = (float)oj * DNS - (float)cc;

    #pragma unroll
    for (int tt = 0; tt < 2; ++tt) {
        int cr0 = 128 * by + 64 * wys + 32 * tt;
        #pragma unroll
        for (int p = 0; p < 8; ++p) {
            // C row for reg 2p: (2p&3) + 8*(2p>>2) + 4*hk ; reg 2p+1 = that row + 1
            int rpe = ((p & 1) << 1) + ((p >> 1) << 3) + 4 * hk;
            int cre = cr0 + rpe;
            int oi = cre >> 1;
            float wyw = (float)oi * DNS - (float)cre;
            float ae, ao;
            if (tt == 0) { ae = acc0[2 * p]; ao = acc0[2 * p + 1]; }
            else         { ae = acc1[2 * p]; ao = acc1[2 * p + 1]; }
            float v = ae + (ao - ae) * wyw;
            float vr = __shfl_xor(v, 1, 64);
            if (doout) {
                float o = v + (vr - v) * wxw;
                out[((size_t)bc * 128 + oi) * 128 + oj] = o;
            }
        }
    }
}

extern "C" void kernel_launch(void* const* d_in, const int* in_sizes, int n_in,
                              void* d_out, int out_size, void* d_ws, size_t ws_size,
                              hipStream_t stream) {
    const float* x    = (const float*)d_in[0];   // (8,64,128,128) f32
    const float* filt = (const float*)d_in[1];   // (31,31) f32
    float* out = (float*)d_out;                  // (8,64,128,128) f32
    unsigned short* tab = (unsigned short*)d_ws; // 31*4*64*8 bf16 = 124 KB

    build_table<<<31, 256, 0, stream>>>(filt, tab);
    dim3 grid(4, 2, 8 * 64);
    afa_mfma<<<grid, dim3(256), 0, stream>>>(x, tab, out);
}

// Round 5
// 174.578 us; speedup vs baseline: 7.1187x; 1.1548x over previous
//
#include <hip/hip_runtime.h>
#include <hip/hip_bf16.h>

typedef __attribute__((ext_vector_type(8))) short bf16x8;
typedef __attribute__((ext_vector_type(16))) float f32x16;

#define INH   128
#define LEAK  0.01f
#define USTR  120          // LDS row stride in bf16 (240B; ≡ 28 mod 32 banks → conflict-free)
#define UROWS 158          // 128 conv rows + 30 halo
#define GSTR  288          // global U row stride in bf16 (15 zero + 256 data + 17 zero)

__device__ __forceinline__ unsigned short f2bf(float f) {
    __hip_bfloat16 h = __float2bfloat16(f);
    return *(unsigned short*)&h;
}

__device__ __forceinline__ float upsample_one(const float* __restrict__ xc,
                                              int ur, int uc, float UPS) {
    float cr = (float)ur * UPS;
    int r0 = (int)cr; if (r0 > 126) r0 = 126;
    float wr = cr - (float)r0;
    float cs = (float)uc * UPS;
    int s0 = (int)cs; if (s0 > 126) s0 = 126;
    float ws = cs - (float)s0;
    const float* p = xc + r0 * INH + s0;
    float a = p[0], b = p[1], c = p[INH], d = p[INH + 1];
    float top = a + (c - a) * wr;          // rows first (reference order)
    float bot = b + (d - b) * wr;
    float val = top + (bot - top) * ws;
    return (val > 0.0f) ? val : (LEAK * val);
}

// ---------- kernel 0: Toeplitz filter fragment table (31*4*64*8 bf16 = 124 KB) ----------
__global__ void build_table(const float* __restrict__ filt, unsigned short* __restrict__ tab) {
    int idx = blockIdx.x * 256 + threadIdx.x;          // (fr*4+c)*64 + lane
    if (idx >= 31 * 4 * 64) return;
    int lane = idx & 63, c = (idx >> 6) & 3, fr = idx >> 8;
    #pragma unroll
    for (int t = 0; t < 8; ++t) {
        int v = 16 * c + 8 * (lane >> 5) + t - (lane & 31);
        float f = (v >= 0 && v <= 30) ? filt[fr * 31 + v] : 0.0f;
        tab[idx * 8 + t] = f2bf(f);
    }
}

// ---------- kernel 1: upsample+leaky_relu -> bf16 U in d_ws (rows 288, zero margins) ----------
__global__ __launch_bounds__(256)
void upsample_act(const float* __restrict__ x, unsigned short* __restrict__ U) {
    const float UPS = (float)(127.0 / 255.0);
    int idx = blockIdx.x * 256 + threadIdx.x;          // unit = 4 bf16 cols (8 B)
    // total units: 512 images * 256 rows * 72
    int bc = idx / (256 * 72);
    int rem = idx - bc * (256 * 72);
    int r = rem / 72;
    int c4 = (rem - r * 72) * 4;
    const float* __restrict__ xc = x + (size_t)bc * (INH * INH);
    unsigned short o[4];
    #pragma unroll
    for (int e = 0; e < 4; ++e) {
        int uc = c4 + e - 15;                          // stored col -> upsampled col
        float val = 0.0f;
        if ((unsigned)uc < 256u) val = upsample_one(xc, r, uc, UPS);
        o[e] = f2bf(val);
    }
    *(uint2*)&U[((size_t)bc * 256 + r) * GSTR + c4] = *(const uint2*)o;
}

// ---------- kernel 2: copy-stage U tile -> MFMA conv -> downsample ----------
__global__ __launch_bounds__(256)
void conv_ds(const unsigned short* __restrict__ U, const unsigned short* __restrict__ tab,
             float* __restrict__ out) {
    __shared__ unsigned short T[UROWS * USTR];         // 37920 B
    const int tid = threadIdx.x;
    const int bx = blockIdx.x;                         // 0..3  (64 conv cols)
    const int by = blockIdx.y;                         // 0..1  (128 conv rows)
    const int bc = blockIdx.z;                         // 0..511
    const float DNS = (float)(255.0 / 127.0);
    const int pr0 = 128 * by, pc0 = 64 * bx;
    const unsigned short* __restrict__ Ub = U + (size_t)bc * 256 * GSTR;

    // ---- stage: 158 rows x 12 chunks of 16B, vertical pad via row predicate ----
    #pragma unroll
    for (int k = 0; k < 8; ++k) {
        int c = tid + k * 256;
        if (c < UROWS * 12) {
            int row = c / 12;
            int sub = c - row * 12;
            int gr = pr0 + row - 15;
            uint4 v = {0u, 0u, 0u, 0u};
            if ((unsigned)gr < 256u)
                v = *(const uint4*)(Ub + gr * GSTR + pc0 + sub * 8);
            *(uint4*)&T[row * USTR + sub * 8] = v;
        }
    }
    __syncthreads();

    // ---- conv: per wave, one 32-col strip x two 32-row tiles; fr-outer, Toeplitz B ----
    const int lane = tid & 63;
    const int w = tid >> 6;
    const int wxs = w & 1, wys = w >> 1;
    const int r32 = lane & 31;                         // A row i (C col j in epilogue)
    const int hk = lane >> 5;                          // k-chunk half

    const char* ub = (const char*)T + (64 * wys + r32) * (USTR * 2) + (32 * wxs + 8 * hk) * 2;
    const bf16x8* tv = (const bf16x8*)tab;

    f32x16 acc0 = {0.f,0.f,0.f,0.f,0.f,0.f,0.f,0.f,0.f,0.f,0.f,0.f,0.f,0.f,0.f,0.f};
    f32x16 acc1 = acc0;

    #pragma unroll 1
    for (int fr = 0; fr < 31; ++fr) {
        bf16x8 B0 = tv[(fr * 4 + 0) * 64 + lane];
        bf16x8 B1 = tv[(fr * 4 + 1) * 64 + lane];
        bf16x8 B2 = tv[(fr * 4 + 2) * 64 + lane];
        bf16x8 B3 = tv[(fr * 4 + 3) * 64 + lane];
        const char* u0 = ub + fr * (USTR * 2);
        const char* u1 = u0 + 32 * (USTR * 2);
        bf16x8 a;
        a = *(const bf16x8*)(u0 + 0);
        acc0 = __builtin_amdgcn_mfma_f32_32x32x16_bf16(a, B0, acc0, 0, 0, 0);
        a = *(const bf16x8*)(u0 + 32);
        acc0 = __builtin_amdgcn_mfma_f32_32x32x16_bf16(a, B1, acc0, 0, 0, 0);
        a = *(const bf16x8*)(u0 + 64);
        acc0 = __builtin_amdgcn_mfma_f32_32x32x16_bf16(a, B2, acc0, 0, 0, 0);
        a = *(const bf16x8*)(u0 + 96);
        acc0 = __builtin_amdgcn_mfma_f32_32x32x16_bf16(a, B3, acc0, 0, 0, 0);
        a = *(const bf16x8*)(u1 + 0);
        acc1 = __builtin_amdgcn_mfma_f32_32x32x16_bf16(a, B0, acc1, 0, 0, 0);
        a = *(const bf16x8*)(u1 + 32);
        acc1 = __builtin_amdgcn_mfma_f32_32x32x16_bf16(a, B1, acc1, 0, 0, 0);
        a = *(const bf16x8*)(u1 + 64);
        acc1 = __builtin_amdgcn_mfma_f32_32x32x16_bf16(a, B2, acc1, 0, 0, 0);
        a = *(const bf16x8*)(u1 + 96);
        acc1 = __builtin_amdgcn_mfma_f32_32x32x16_bf16(a, B3, acc1, 0, 0, 0);
    }

    // ---- epilogue: bilinear downsample (rows in-lane via reg pairs, cols via shfl_xor) ----
    const int cc = 64 * bx + 32 * wxs + r32;
    const bool doout = (cc & 1) == 0;
    const int oj = cc >> 1;
    const float wxw = (float)oj * DNS - (float)cc;

    #pragma unroll
    for (int tt = 0; tt < 2; ++tt) {
        int cr0 = 128 * by + 64 * wys + 32 * tt;
        #pragma unroll
        for (int p = 0; p < 8; ++p) {
            int rpe = ((p & 1) << 1) + ((p >> 1) << 3) + 4 * hk;
            int cre = cr0 + rpe;
            int oi = cre >> 1;
            float wyw = (float)oi * DNS - (float)cre;
            float ae, ao;
            if (tt == 0) { ae = acc0[2 * p]; ao = acc0[2 * p + 1]; }
            else         { ae = acc1[2 * p]; ao = acc1[2 * p + 1]; }
            float v = ae + (ao - ae) * wyw;
            float vr = __shfl_xor(v, 1, 64);
            if (doout) {
                float o = v + (vr - v) * wxw;
                out[((size_t)bc * 128 + oi) * 128 + oj] = o;
            }
        }
    }
}

// ---------- fallback (round-4 fused kernel) if ws too small for U ----------
__global__ __launch_bounds__(256)
void afa_mfma(const float* __restrict__ x, const unsigned short* __restrict__ tab,
              float* __restrict__ out) {
    __shared__ unsigned short Ut[UROWS * USTR];
    const int tid = threadIdx.x;
    const int bx = blockIdx.x, by = blockIdx.y, bc = blockIdx.z;
    const float* __restrict__ xc = x + (size_t)bc * (INH * INH);
    const float UPS = (float)(127.0 / 255.0);
    const float DNS = (float)(255.0 / 127.0);
    const int pr0 = 128 * by, pc0 = 64 * bx;

    for (int idx = tid; idx < UROWS * (USTR / 2); idx += 256) {
        int lr = idx / (USTR / 2);
        int lc0 = (idx - lr * (USTR / 2)) * 2;
        unsigned pack = 0;
        #pragma unroll
        for (int e = 0; e < 2; ++e) {
            int lc = lc0 + e;
            int ur = pr0 + lr - 15;
            int uc = pc0 + lc - 15;
            float val = 0.0f;
            if (lc < 96 && (unsigned)ur < 256u && (unsigned)uc < 256u)
                val = upsample_one(xc, ur, uc, UPS);
            pack |= (unsigned)f2bf(val) << (16 * e);
        }
        *(unsigned*)&Ut[lr * USTR + lc0] = pack;
    }
    __syncthreads();

    const int lane = tid & 63;
    const int w = tid >> 6;
    const int wxs = w & 1, wys = w >> 1;
    const int r32 = lane & 31;
    const int hk = lane >> 5;
    const char* ub = (const char*)Ut + (64 * wys + r32) * (USTR * 2) + (32 * wxs + 8 * hk) * 2;
    const bf16x8* tv = (const bf16x8*)tab;
    f32x16 acc0 = {0.f,0.f,0.f,0.f,0.f,0.f,0.f,0.f,0.f,0.f,0.f,0.f,0.f,0.f,0.f,0.f};
    f32x16 acc1 = acc0;

    #pragma unroll 1
    for (int fr = 0; fr < 31; ++fr) {
        bf16x8 B0 = tv[(fr * 4 + 0) * 64 + lane];
        bf16x8 B1 = tv[(fr * 4 + 1) * 64 + lane];
        bf16x8 B2 = tv[(fr * 4 + 2) * 64 + lane];
        bf16x8 B3 = tv[(fr * 4 + 3) * 64 + lane];
        const char* u0 = ub + fr * (USTR * 2);
        const char* u1 = u0 + 32 * (USTR * 2);
        bf16x8 a;
        a = *(const bf16x8*)(u0 + 0);
        acc0 = __builtin_amdgcn_mfma_f32_32x32x16_bf16(a, B0, acc0, 0, 0, 0);
        a = *(const bf16x8*)(u0 + 32);
        acc0 = __builtin_amdgcn_mfma_f32_32x32x16_bf16(a, B1, acc0, 0, 0, 0);
        a = *(const bf16x8*)(u0 + 64);
        acc0 = __builtin_amdgcn_mfma_f32_32x32x16_bf16(a, B2, acc0, 0, 0, 0);
        a = *(const bf16x8*)(u0 + 96);
        acc0 = __builtin_amdgcn_mfma_f32_32x32x16_bf16(a, B3, acc0, 0, 0, 0);
        a = *(const bf16x8*)(u1 + 0);
        acc1 = __builtin_amdgcn_mfma_f32_32x32x16_bf16(a, B0, acc1, 0, 0, 0);
        a = *(const bf16x8*)(u1 + 32);
        acc1 = __builtin_amdgcn_mfma_f32_32x32x16_bf16(a, B1, acc1, 0, 0, 0);
        a = *(const bf16x8*)(u1 + 64);
        acc1 = __builtin_amdgcn_mfma_f32_32x32x16_bf16(a, B2, acc1, 0, 0, 0);
        a = *(const bf16x8*)(u1 + 96);
        acc1 = __builtin_amdgcn_mfma_f32_32x32x16_bf16(a, B3, acc1, 0, 0, 0);
    }

    const int cc = 64 * bx + 32 * wxs + r32;
    const bool doout = (cc & 1) == 0;
    const int oj = cc >> 1;
    const float wxw = (float)oj * DNS - (float)cc;
    #pragma unroll
    for (int tt = 0; tt < 2; ++tt) {
        int cr0 = 128 * by + 64 * wys + 32 * tt;
        #pragma unroll
        for (int p = 0; p < 8; ++p) {
            int rpe = ((p & 1) << 1) + ((p >> 1) << 3) + 4 * hk;
            int cre = cr0 + rpe;
            int oi = cre >> 1;
            float wyw = (float)oi * DNS - (float)cre;
            float ae, ao;
            if (tt == 0) { ae = acc0[2 * p]; ao = acc0[2 * p + 1]; }
            else         { ae = acc1[2 * p]; ao = acc1[2 * p + 1]; }
            float v = ae + (ao - ae) * wyw;
            float vr = __shfl_xor(v, 1, 64);
            if (doout) {
                float o = v + (vr - v) * wxw;
                out[((size_t)bc * 128 + oi) * 128 + oj] = o;
            }
        }
    }
}

extern "C" void kernel_launch(void* const* d_in, const int* in_sizes, int n_in,
                              void* d_out, int out_size, void* d_ws, size_t ws_size,
                              hipStream_t stream) {
    const float* x    = (const float*)d_in[0];   // (8,64,128,128) f32
    const float* filt = (const float*)d_in[1];   // (31,31) f32
    float* out = (float*)d_out;                  // (8,64,128,128) f32

    unsigned short* tab = (unsigned short*)d_ws;                 // 124 KB @ offset 0
    const size_t U_OFF  = 131072;                                // 128 KB
    const size_t U_NEED = U_OFF + (size_t)512 * 256 * GSTR * 2;  // ~75.6 MB

    build_table<<<31, 256, 0, stream>>>(filt, tab);

    if (ws_size >= U_NEED) {
        unsigned short* U = (unsigned short*)((char*)d_ws + U_OFF);
        upsample_act<<<512 * 256 * 72 / 256, 256, 0, stream>>>(x, U);
        dim3 grid(4, 2, 8 * 64);
        conv_ds<<<grid, dim3(256), 0, stream>>>(U, tab, out);
    } else {
        dim3 grid(4, 2, 8 * 64);
        afa_mfma<<<grid, dim3(256), 0, stream>>>(x, tab, out);
    }
}

// Round 7
// 165.561 us; speedup vs baseline: 7.5064x; 1.0545x over previous
//
#include <hip/hip_runtime.h>
#include <hip/hip_bf16.h>

typedef __attribute__((ext_vector_type(8))) short bf16x8;
typedef __attribute__((ext_vector_type(16))) float f32x16;

#define INH   128
#define LEAK  0.01f
#define GSTR  288          // U row stride in bf16 (15 zero + 256 data + 17 zero)
#define TSTR  168          // LDS tile stride in bf16 (336B, 16B-multiple)
#define TROWS 94           // 64 conv rows + 30 halo

__device__ __forceinline__ unsigned short f2bf(float f) {
    __hip_bfloat16 h = __float2bfloat16(f);
    return *(unsigned short*)&h;
}

__device__ __forceinline__ float upsample_one(const float* __restrict__ xc,
                                              int ur, int uc, float UPS) {
    float cr = (float)ur * UPS;
    int r0 = (int)cr; if (r0 > 126) r0 = 126;
    float wr = cr - (float)r0;
    float cs = (float)uc * UPS;
    int s0 = (int)cs; if (s0 > 126) s0 = 126;
    float ws = cs - (float)s0;
    const float* p = xc + r0 * INH + s0;
    float a = p[0], b = p[1], c = p[INH], d = p[INH + 1];
    float top = a + (c - a) * wr;          // rows first (reference order)
    float bot = b + (d - b) * wr;
    float val = top + (bot - top) * ws;
    return (val > 0.0f) ? val : (LEAK * val);
}

// ---------- table builder (standalone, for fallback path) ----------
__global__ void build_table(const float* __restrict__ filt, unsigned short* __restrict__ tab) {
    int idx = blockIdx.x * 256 + threadIdx.x;          // (fr*4+c)*64 + lane
    if (idx >= 31 * 4 * 64) return;
    int lane = idx & 63, c = (idx >> 6) & 3, fr = idx >> 8;
    #pragma unroll
    for (int t = 0; t < 8; ++t) {
        int v = 16 * c + 8 * (lane >> 5) + t - (lane & 31);
        float f = (v >= 0 && v <= 30) ? filt[fr * 31 + v] : 0.0f;
        tab[idx * 8 + t] = f2bf(f);
    }
}

// ---------- kernel 1: table build (blocks 0..30) + upsample+act -> U (blocks 31..) ----------
__global__ __launch_bounds__(256)
void up_table(const float* __restrict__ x, const float* __restrict__ filt,
              unsigned short* __restrict__ U, unsigned short* __restrict__ tab) {
    const int tid = threadIdx.x;
    if (blockIdx.x < 31) {
        int idx = blockIdx.x * 256 + tid;
        if (idx >= 31 * 4 * 64) return;
        int lane = idx & 63, c = (idx >> 6) & 3, fr = idx >> 8;
        #pragma unroll
        for (int t = 0; t < 8; ++t) {
            int v = 16 * c + 8 * (lane >> 5) + t - (lane & 31);
            float f = (v >= 0 && v <= 30) ? filt[fr * 31 + v] : 0.0f;
            tab[idx * 8 + t] = f2bf(f);
        }
        return;
    }
    const float UPS = (float)(127.0 / 255.0);
    int idx = (blockIdx.x - 31) * 256 + tid;           // unit = 4 bf16 cols (8 B)
    int bc = idx / (256 * 72);
    int rem = idx - bc * (256 * 72);
    int r = rem / 72;
    int c4 = (rem - r * 72) * 4;
    const float* __restrict__ xc = x + (size_t)bc * (INH * INH);
    unsigned short o[4];
    #pragma unroll
    for (int e = 0; e < 4; ++e) {
        int uc = c4 + e - 15;
        float val = 0.0f;
        if ((unsigned)uc < 256u) val = upsample_one(xc, r, uc, UPS);
        o[e] = f2bf(val);
    }
    *(uint2*)&U[((size_t)bc * 256 + r) * GSTR + c4] = *(const uint2*)o;
}

// ---------- kernel 2: copy-stage -> MFMA conv (A-chunk-shared strips) -> downsample ----------
__global__ __launch_bounds__(256, 4)
void conv_ds(const unsigned short* __restrict__ U, const unsigned short* __restrict__ tab,
             float* __restrict__ out) {
    __shared__ unsigned short T[TROWS * TSTR];         // 31584 B
    const int tid = threadIdx.x;
    const int bx = blockIdx.x;                         // 0..1 (128 conv cols)
    const int by = blockIdx.y;                         // 0..3 (64 conv rows)
    const int bc = blockIdx.z;                         // 0..511
    const float DNS = (float)(255.0 / 127.0);
    const int pr0 = 64 * by;
    const unsigned short* __restrict__ Ub = U + (size_t)bc * 256 * GSTR + bx * 128;

    // ---- stage: 94 rows x 20 uint4 (160 bf16 cols), vertical pad via row predicate ----
    #pragma unroll
    for (int k = 0; k < 8; ++k) {
        int c = tid + k * 256;
        if (c < TROWS * 20) {
            int row = c / 20;
            int sub = c - row * 20;
            int gr = pr0 + row - 15;
            uint4 v = {0u, 0u, 0u, 0u};
            if ((unsigned)gr < 256u)
                v = *(const uint4*)(Ub + gr * GSTR + sub * 8);
            *(uint4*)&T[row * TSTR + sub * 8] = v;
        }
    }
    __syncthreads();

    // ---- conv: wave = 32 rows x 64 cols (2 col strips sharing A-chunks 2..3) ----
    const int lane = tid & 63;
    const int w = tid >> 6;
    const int wxs = w & 1;                             // col half within block
    const int band = w >> 1;                           // 32-row band within block
    const int r32 = lane & 31;                         // A row i (C col j in epilogue)
    const int hk = lane >> 5;                          // k-chunk half

    const char* ab = (const char*)T + (32 * band + r32) * (TSTR * 2) + (64 * wxs + 8 * hk) * 2;
    const bf16x8* tv = (const bf16x8*)tab;

    f32x16 acc0 = {0.f,0.f,0.f,0.f,0.f,0.f,0.f,0.f,0.f,0.f,0.f,0.f,0.f,0.f,0.f,0.f};
    f32x16 acc1 = acc0;

    #pragma unroll 2
    for (int fr = 0; fr < 31; ++fr) {
        bf16x8 B0 = tv[(fr * 4 + 0) * 64 + lane];
        bf16x8 B1 = tv[(fr * 4 + 1) * 64 + lane];
        bf16x8 B2 = tv[(fr * 4 + 2) * 64 + lane];
        bf16x8 B3 = tv[(fr * 4 + 3) * 64 + lane];
        const char* u = ab + fr * (TSTR * 2);
        bf16x8 A0 = *(const bf16x8*)(u + 0);
        bf16x8 A1 = *(const bf16x8*)(u + 32);
        bf16x8 A2 = *(const bf16x8*)(u + 64);
        bf16x8 A3 = *(const bf16x8*)(u + 96);
        bf16x8 A4 = *(const bf16x8*)(u + 128);
        bf16x8 A5 = *(const bf16x8*)(u + 160);
        // strip0 uses chunks 0..3, strip1 uses chunks 2..5 with the SAME B-frags
        acc0 = __builtin_amdgcn_mfma_f32_32x32x16_bf16(A0, B0, acc0, 0, 0, 0);
        acc1 = __builtin_amdgcn_mfma_f32_32x32x16_bf16(A2, B0, acc1, 0, 0, 0);
        acc0 = __builtin_amdgcn_mfma_f32_32x32x16_bf16(A1, B1, acc0, 0, 0, 0);
        acc1 = __builtin_amdgcn_mfma_f32_32x32x16_bf16(A3, B1, acc1, 0, 0, 0);
        acc0 = __builtin_amdgcn_mfma_f32_32x32x16_bf16(A2, B2, acc0, 0, 0, 0);
        acc1 = __builtin_amdgcn_mfma_f32_32x32x16_bf16(A4, B2, acc1, 0, 0, 0);
        acc0 = __builtin_amdgcn_mfma_f32_32x32x16_bf16(A3, B3, acc0, 0, 0, 0);
        acc1 = __builtin_amdgcn_mfma_f32_32x32x16_bf16(A5, B3, acc1, 0, 0, 0);
    }

    // ---- epilogue: bilinear downsample (rows in-lane via reg pairs, cols via shfl_xor) ----
    #pragma unroll
    for (int s = 0; s < 2; ++s) {
        int cc = 128 * bx + 64 * wxs + 32 * s + r32;    // conv col (C col j)
        const bool doout = (cc & 1) == 0;
        const int oj = cc >> 1;
        const float wxw = (float)oj * DNS - (float)cc;
        #pragma unroll
        for (int p = 0; p < 8; ++p) {
            int rpe = ((p & 1) << 1) + ((p >> 1) << 3) + 4 * hk;   // even C row of reg 2p
            int cre = 64 * by + 32 * band + rpe;
            int oi = cre >> 1;
            float wyw = (float)oi * DNS - (float)cre;
            float ae, ao;
            if (s == 0) { ae = acc0[2 * p]; ao = acc0[2 * p + 1]; }
            else        { ae = acc1[2 * p]; ao = acc1[2 * p + 1]; }
            float v = ae + (ao - ae) * wyw;
            float vr = __shfl_xor(v, 1, 64);
            if (doout) {
                float o = v + (vr - v) * wxw;
                out[((size_t)bc * 128 + oi) * 128 + oj] = o;
            }
        }
    }
}

// ---------- fallback (round-4 fused kernel) if ws too small for U ----------
#define FUSTR  120
#define FUROWS 158
__global__ __launch_bounds__(256)
void afa_mfma(const float* __restrict__ x, const unsigned short* __restrict__ tab,
              float* __restrict__ out) {
    __shared__ unsigned short Ut[FUROWS * FUSTR];
    const int tid = threadIdx.x;
    const int bx = blockIdx.x, by = blockIdx.y, bc = blockIdx.z;
    const float* __restrict__ xc = x + (size_t)bc * (INH * INH);
    const float UPS = (float)(127.0 / 255.0);
    const float DNS = (float)(255.0 / 127.0);
    const int pr0 = 128 * by, pc0 = 64 * bx;

    for (int idx = tid; idx < FUROWS * (FUSTR / 2); idx += 256) {
        int lr = idx / (FUSTR / 2);
        int lc0 = (idx - lr * (FUSTR / 2)) * 2;
        unsigned pack = 0;
        #pragma unroll
        for (int e = 0; e < 2; ++e) {
            int lc = lc0 + e;
            int ur = pr0 + lr - 15;
            int uc = pc0 + lc - 15;
            float val = 0.0f;
            if (lc < 96 && (unsigned)ur < 256u && (unsigned)uc < 256u)
                val = upsample_one(xc, ur, uc, UPS);
            pack |= (unsigned)f2bf(val) << (16 * e);
        }
        *(unsigned*)&Ut[lr * FUSTR + lc0] = pack;
    }
    __syncthreads();

    const int lane = tid & 63;
    const int w = tid >> 6;
    const int wxs = w & 1, wys = w >> 1;
    const int r32 = lane & 31;
    const int hk = lane >> 5;
    const char* ub = (const char*)Ut + (64 * wys + r32) * (FUSTR * 2) + (32 * wxs + 8 * hk) * 2;
    const bf16x8* tv = (const bf16x8*)tab;
    f32x16 acc0 = {0.f,0.f,0.f,0.f,0.f,0.f,0.f,0.f,0.f,0.f,0.f,0.f,0.f,0.f,0.f,0.f};
    f32x16 acc1 = acc0;

    #pragma unroll 1
    for (int fr = 0; fr < 31; ++fr) {
        bf16x8 B0 = tv[(fr * 4 + 0) * 64 + lane];
        bf16x8 B1 = tv[(fr * 4 + 1) * 64 + lane];
        bf16x8 B2 = tv[(fr * 4 + 2) * 64 + lane];
        bf16x8 B3 = tv[(fr * 4 + 3) * 64 + lane];
        const char* u0 = ub + fr * (FUSTR * 2);
        const char* u1 = u0 + 32 * (FUSTR * 2);
        bf16x8 a;
        a = *(const bf16x8*)(u0 + 0);
        acc0 = __builtin_amdgcn_mfma_f32_32x32x16_bf16(a, B0, acc0, 0, 0, 0);
        a = *(const bf16x8*)(u0 + 32);
        acc0 = __builtin_amdgcn_mfma_f32_32x32x16_bf16(a, B1, acc0, 0, 0, 0);
        a = *(const bf16x8*)(u0 + 64);
        acc0 = __builtin_amdgcn_mfma_f32_32x32x16_bf16(a, B2, acc0, 0, 0, 0);
        a = *(const bf16x8*)(u0 + 96);
        acc0 = __builtin_amdgcn_mfma_f32_32x32x16_bf16(a, B3, acc0, 0, 0, 0);
        a = *(const bf16x8*)(u1 + 0);
        acc1 = __builtin_amdgcn_mfma_f32_32x32x16_bf16(a, B0, acc1, 0, 0, 0);
        a = *(const bf16x8*)(u1 + 32);
        acc1 = __builtin_amdgcn_mfma_f32_32x32x16_bf16(a, B1, acc1, 0, 0, 0);
        a = *(const bf16x8*)(u1 + 64);
        acc1 = __builtin_amdgcn_mfma_f32_32x32x16_bf16(a, B2, acc1, 0, 0, 0);
        a = *(const bf16x8*)(u1 + 96);
        acc1 = __builtin_amdgcn_mfma_f32_32x32x16_bf16(a, B3, acc1, 0, 0, 0);
    }

    const int cc = 64 * bx + 32 * wxs + r32;
    const bool doout = (cc & 1) == 0;
    const int oj = cc >> 1;
    const float wxw = (float)oj * DNS - (float)cc;
    #pragma unroll
    for (int tt = 0; tt < 2; ++tt) {
        int cr0 = 128 * by + 64 * wys + 32 * tt;
        #pragma unroll
        for (int p = 0; p < 8; ++p) {
            int rpe = ((p & 1) << 1) + ((p >> 1) << 3) + 4 * hk;
            int cre = cr0 + rpe;
            int oi = cre >> 1;
            float wyw = (float)oi * DNS - (float)cre;
            float ae, ao;
            if (tt == 0) { ae = acc0[2 * p]; ao = acc0[2 * p + 1]; }
            else         { ae = acc1[2 * p]; ao = acc1[2 * p + 1]; }
            float v = ae + (ao - ae) * wyw;
            float vr = __shfl_xor(v, 1, 64);
            if (doout) {
                float o = v + (vr - v) * wxw;
                out[((size_t)bc * 128 + oi) * 128 + oj] = o;
            }
        }
    }
}

extern "C" void kernel_launch(void* const* d_in, const int* in_sizes, int n_in,
                              void* d_out, int out_size, void* d_ws, size_t ws_size,
                              hipStream_t stream) {
    const float* x    = (const float*)d_in[0];   // (8,64,128,128) f32
    const float* filt = (const float*)d_in[1];   // (31,31) f32
    float* out = (float*)d_out;                  // (8,64,128,128) f32

    unsigned short* tab = (unsigned short*)d_ws;                 // 124 KB @ offset 0
    const size_t U_OFF  = 131072;                                // 128 KB
    const size_t U_NEED = U_OFF + (size_t)512 * 256 * GSTR * 2;  // ~75.6 MB

    if (ws_size >= U_NEED) {
        unsigned short* U = (unsigned short*)((char*)d_ws + U_OFF);
        up_table<<<31 + 512 * 256 * 72 / 256, 256, 0, stream>>>(x, filt, U, tab);
        dim3 grid(2, 4, 8 * 64);
        conv_ds<<<grid, dim3(256), 0, stream>>>(U, tab, out);
    } else {
        build_table<<<31, 256, 0, stream>>>(filt, tab);
        dim3 grid(4, 2, 8 * 64);
        afa_mfma<<<grid, dim3(256), 0, stream>>>(x, tab, out);
    }
}